// Round 5
// baseline (363.594 us; speedup 1.0000x reference)
//
#include <hip/hip_runtime.h>
#include <stdint.h>

typedef unsigned short u16;
typedef unsigned int   u32;
typedef __attribute__((ext_vector_type(8))) short  short8;   // 8 x bf16 (4 VGPRs)
typedef __attribute__((ext_vector_type(4))) float  floatx4;  // MFMA acc

__device__ __forceinline__ u16 f32_to_bf16(float f) {
  u32 u = __builtin_bit_cast(u32, f);
  u = (u + 0x7fffu + ((u >> 16) & 1u)) >> 16;
  return (u16)u;
}
__device__ __forceinline__ float bf16_to_f32(u16 h) {
  u32 u = ((u32)h) << 16;
  return __builtin_bit_cast(float, u);
}
__device__ __forceinline__ float bf16_lo(u32 u) {
  return __builtin_bit_cast(float, u << 16);
}
__device__ __forceinline__ float bf16_hi(u32 u) {
  return __builtin_bit_cast(float, u & 0xffff0000u);
}

// async global->LDS, 16B per lane. LDS dst = wave-uniform base + lane*16.
__device__ __forceinline__ void load_lds16(const u16* g, u16* l) {
  auto gp = (const __attribute__((address_space(1))) u32*)(uintptr_t)g;
  auto lp = (__attribute__((address_space(3))) u32*)(u32)(uintptr_t)l;
  __builtin_amdgcn_global_load_lds(gp, lp, 16, 0, 0);
}

// ---------------------------------------------------------------------------
// K1: fused QKV 1x1 conv + patch-token scatter. STREAMING version:
// one wave per w-row; lane l owns h = 4l..4l+3 (float4 = 1 KB/wave-load,
// fully contiguous). No LDS. Per-pixel store formulas mechanically derived
// from the verified R4 LDS path:
//   N(w,h) = ((h>>4)&7)*128 + ((h>>3)&1)*64 + (w&7)*8 + (h&7)
//   M(cq,w,h) = cq*64 + (w>>3)*2 + (h>>7)
//   qt/kt flat = (b*1024+N)*512 + M ;  vm flat = (b*512+M)*1024 + N
// ---------------------------------------------------------------------------
__global__ __launch_bounds__(256) void qkv_kernel(
    const float* __restrict__ x,
    const float* __restrict__ Wq, const float* __restrict__ bq,
    const float* __restrict__ Wk, const float* __restrict__ bk,
    const float* __restrict__ Wv, const float* __restrict__ bv,
    u16* __restrict__ qt, u16* __restrict__ kt, u16* __restrict__ vm)
{
  const int t = threadIdx.x;
  const int wv = t >> 6, l = t & 63;
  const int w = blockIdx.x * 4 + wv;      // 0..255
  const int b = blockIdx.y;               // 0..7
  const int h0 = l << 2;                  // 4 consecutive h per lane

  // x[b][c][w][h0..h0+3], channel stride 65536 floats = 16384 float4
  const float4* xq = (const float4*)(x + (size_t)b * 4194304 + w * 256 + h0);

  float aq[8][4], ak[8][4], av[8][4];
#pragma unroll
  for (int cq = 0; cq < 8; cq++)
#pragma unroll
    for (int p = 0; p < 4; p++) { aq[cq][p] = 0.f; ak[cq][p] = 0.f; av[cq][p] = 0.f; }

  float4 x0 = xq[0];
  float4 x1 = xq[16384];
#pragma unroll 2
  for (int c = 0; c < 64; c++) {
    float4 cur = x0;
    x0 = x1;
    int cn = c + 2 < 64 ? c + 2 : 63;     // clamped prefetch (no OOB)
    x1 = xq[(size_t)cn * 16384];
#pragma unroll
    for (int cq = 0; cq < 8; cq++) {
      float wqc = Wq[cq * 64 + c], wkc = Wk[cq * 64 + c], wvc = Wv[cq * 64 + c];
      aq[cq][0] = fmaf(wqc, cur.x, aq[cq][0]);
      aq[cq][1] = fmaf(wqc, cur.y, aq[cq][1]);
      aq[cq][2] = fmaf(wqc, cur.z, aq[cq][2]);
      aq[cq][3] = fmaf(wqc, cur.w, aq[cq][3]);
      ak[cq][0] = fmaf(wkc, cur.x, ak[cq][0]);
      ak[cq][1] = fmaf(wkc, cur.y, ak[cq][1]);
      ak[cq][2] = fmaf(wkc, cur.z, ak[cq][2]);
      ak[cq][3] = fmaf(wkc, cur.w, ak[cq][3]);
      av[cq][0] = fmaf(wvc, cur.x, av[cq][0]);
      av[cq][1] = fmaf(wvc, cur.y, av[cq][1]);
      av[cq][2] = fmaf(wvc, cur.z, av[cq][2]);
      av[cq][3] = fmaf(wvc, cur.w, av[cq][3]);
    }
  }

  // Epilogue: direct per-pixel stores.
  const int hh = l >> 5;                                   // h>>7 for all 4 px
  const int Mb = ((w >> 3) << 1) + hh;                     // M minus cq*64
  const int N0 = ((l >> 2) & 7) * 128 + ((l >> 1) & 1) * 64 + (w & 7) * 8 + ((l & 1) << 2);
  const size_t qtbase = ((size_t)b * 1024 + N0) * 512 + Mb;

#pragma unroll
  for (int cq = 0; cq < 8; cq++) {
    const float bqc = bq[cq], bkc = bk[cq], bvc = bv[cq];
    const size_t o = qtbase + cq * 64;
#pragma unroll
    for (int j = 0; j < 4; j++) {
      qt[o + (size_t)j * 512] = f32_to_bf16(aq[cq][j] + bqc);
      kt[o + (size_t)j * 512] = f32_to_bf16(ak[cq][j] + bkc);
    }
    ushort4 pv;
    pv.x = f32_to_bf16(av[cq][0] + bvc);
    pv.y = f32_to_bf16(av[cq][1] + bvc);
    pv.z = f32_to_bf16(av[cq][2] + bvc);
    pv.w = f32_to_bf16(av[cq][3] + bvc);
    *(ushort4*)(vm + ((size_t)b * 512 + cq * 64 + Mb) * 1024 + N0) = pv;
  }
}

// ---------------------------------------------------------------------------
// NT GEMM: C[M][N] = scale * A[M][K] * B[N][K]^T  (unchanged from R2)
// Tile BM(=FMW*32) x 128, BK=64, XOR-swizzled LDS.
// ---------------------------------------------------------------------------
template <int FMW>
__global__ __launch_bounds__(256) void gemm_nt(
    const u16* __restrict__ A, const u16* __restrict__ Bm, u16* __restrict__ Cm,
    int M, int N, int K, float scale)
{
  constexpr int BM = FMW * 32;
  __shared__ __align__(16) u16 As[BM * 64];
  __shared__ __align__(16) u16 Bs[128 * 64];

  const int bn = blockIdx.x, bm = blockIdx.y, bz = blockIdx.z;
  const int t = threadIdx.x;
  const int lane = t & 63, wid = t >> 6;
  const int wm = wid & 1, wn = wid >> 1;
  const int m0 = bm * BM, n0 = bn * 128;

  const u16* Ab = A + (size_t)bz * M * K + (size_t)m0 * K;
  const u16* Bb = Bm + (size_t)bz * N * K + (size_t)n0 * K;

  floatx4 acc[FMW][4];
#pragma unroll
  for (int i = 0; i < FMW; i++)
#pragma unroll
    for (int j = 0; j < 4; j++) acc[i][j] = (floatx4){0.f, 0.f, 0.f, 0.f};

  const int srow = wid * 8 + (lane >> 3);
  const int scol = (((lane & 7) ^ ((lane >> 3) & 7)) << 3);
  const int l15 = lane & 15, quad = lane >> 4;
  const int cxor = (l15 & 7) << 3;

  for (int k0 = 0; k0 < K; k0 += 64) {
#pragma unroll
    for (int i = 0; i < FMW; i++)
      load_lds16(Ab + (size_t)(i * 32 + srow) * K + k0 + scol, As + (i * 32 + wid * 8) * 64);
#pragma unroll
    for (int i = 0; i < 4; i++)
      load_lds16(Bb + (size_t)(i * 32 + srow) * K + k0 + scol, Bs + (i * 32 + wid * 8) * 64);
    __syncthreads();
#pragma unroll
    for (int ks = 0; ks < 2; ks++) {
      const int koff = (ks * 32 + quad * 8) ^ cxor;
      short8 a[FMW], b[4];
#pragma unroll
      for (int f = 0; f < FMW; f++)
        a[f] = *(const short8*)(As + (wm * FMW * 16 + f * 16 + l15) * 64 + koff);
#pragma unroll
      for (int f = 0; f < 4; f++)
        b[f] = *(const short8*)(Bs + (wn * 64 + f * 16 + l15) * 64 + koff);
#pragma unroll
      for (int fm = 0; fm < FMW; fm++)
#pragma unroll
        for (int fn = 0; fn < 4; fn++)
          acc[fm][fn] = __builtin_amdgcn_mfma_f32_16x16x32_bf16(a[fm], b[fn], acc[fm][fn], 0, 0, 0);
    }
    __syncthreads();
  }

  u16* Cb = Cm + (size_t)bz * M * N;
#pragma unroll
  for (int fm = 0; fm < FMW; fm++)
#pragma unroll
    for (int fn = 0; fn < 4; fn++)
#pragma unroll
      for (int r = 0; r < 4; r++) {
        int row = m0 + wm * FMW * 16 + fm * 16 + quad * 4 + r;
        int col = n0 + wn * 64 + fn * 16 + l15;
        Cb[(size_t)row * N + col] = f32_to_bf16(scale * acc[fm][fn][r]);
      }
}

// ---------------------------------------------------------------------------
// Softmax: one 1024-wide row per WAVE (shuffle-only, no LDS/syncthreads).
// ---------------------------------------------------------------------------
__global__ __launch_bounds__(256) void softmax_kernel(u16* __restrict__ EP)
{
  const int lane = threadIdx.x & 63, wid = threadIdx.x >> 6;
  const int r = blockIdx.x * 4 + wid;           // 0..8191
  u32* row = (u32*)(EP + (size_t)r * 1024);     // 512 u32

  uint4 c0 = ((const uint4*)row)[lane];
  uint4 c1 = ((const uint4*)row)[64 + lane];
  u32 u[8] = {c0.x, c0.y, c0.z, c0.w, c1.x, c1.y, c1.z, c1.w};
  float e[16];
#pragma unroll
  for (int i = 0; i < 8; i++) { e[2 * i] = bf16_lo(u[i]); e[2 * i + 1] = bf16_hi(u[i]); }

  float mx = e[0];
#pragma unroll
  for (int i = 1; i < 16; i++) mx = fmaxf(mx, e[i]);
#pragma unroll
  for (int off = 32; off > 0; off >>= 1) mx = fmaxf(mx, __shfl_xor(mx, off));

  float s = 0.f;
#pragma unroll
  for (int i = 0; i < 16; i++) { e[i] = __expf(e[i] - mx); s += e[i]; }
#pragma unroll
  for (int off = 32; off > 0; off >>= 1) s += __shfl_xor(s, off);

  float inv = 1.0f / s;
#pragma unroll
  for (int i = 0; i < 8; i++)
    u[i] = (u32)f32_to_bf16(e[2 * i] * inv) | ((u32)f32_to_bf16(e[2 * i + 1] * inv) << 16);
  ((uint4*)row)[lane]      = (uint4){u[0], u[1], u[2], u[3]};
  ((uint4*)row)[64 + lane] = (uint4){u[4], u[5], u[6], u[7]};
}

// ---------------------------------------------------------------------------
// K5: out = gamma*(Wo . OT + bo) + x. 4 consecutive pixels per thread,
// float4 x-loads / out-stores.
// ---------------------------------------------------------------------------
__global__ __launch_bounds__(256) void out_kernel(
    const float* __restrict__ x, const u16* __restrict__ OT,
    const float* __restrict__ Wo, const float* __restrict__ bo,
    const float* __restrict__ gammap, float* __restrict__ out)
{
  const int tid = blockIdx.x * 256 + threadIdx.x;   // 0..131071
  const int pix = tid << 2;                          // 4-aligned
  const int b = pix >> 16, rem = pix & 65535;
  const float g = gammap[0];

  const u16* otb = OT + (size_t)b * 524288;
  const int m = rem & 511;
  const int nbase = rem >> 9;
  float oc[8][4];
#pragma unroll
  for (int cq = 0; cq < 8; cq++) {
    ushort4 hv = *(const ushort4*)(otb + (size_t)(cq * 128 + nbase) * 512 + m);
    oc[cq][0] = bf16_to_f32(hv.x); oc[cq][1] = bf16_to_f32(hv.y);
    oc[cq][2] = bf16_to_f32(hv.z); oc[cq][3] = bf16_to_f32(hv.w);
  }

  const float4* xb4 = (const float4*)(x + (size_t)b * 4194304 + rem);
  float4* ob4 = (float4*)(out + (size_t)b * 4194304 + rem);
#pragma unroll 4
  for (int o = 0; o < 64; o++) {
    float4 xv = xb4[o * 16384];
    float a0 = bo[o], a1 = a0, a2 = a0, a3 = a0;
#pragma unroll
    for (int cq = 0; cq < 8; cq++) {
      float wv = Wo[o * 8 + cq];
      a0 = fmaf(wv, oc[cq][0], a0);
      a1 = fmaf(wv, oc[cq][1], a1);
      a2 = fmaf(wv, oc[cq][2], a2);
      a3 = fmaf(wv, oc[cq][3], a3);
    }
    float4 r;
    r.x = fmaf(g, a0, xv.x); r.y = fmaf(g, a1, xv.y);
    r.z = fmaf(g, a2, xv.z); r.w = fmaf(g, a3, xv.w);
    ob4[o * 16384] = r;
  }
}

// ---------------------------------------------------------------------------
extern "C" void kernel_launch(void* const* d_in, const int* in_sizes, int n_in,
                              void* d_out, int out_size, void* d_ws, size_t ws_size,
                              hipStream_t stream) {
  const float* x  = (const float*)d_in[0];
  const float* Wq = (const float*)d_in[1];
  const float* bq = (const float*)d_in[2];
  const float* Wk = (const float*)d_in[3];
  const float* bk = (const float*)d_in[4];
  const float* Wv = (const float*)d_in[5];
  const float* bv = (const float*)d_in[6];
  const float* Wo = (const float*)d_in[7];
  const float* bo = (const float*)d_in[8];
  const float* gm = (const float*)d_in[9];
  float* out = (float*)d_out;

  // workspace carve: qt | kt | v | EP ; OT reuses qt (dead after gemm1)
  u16* qt = (u16*)d_ws;            // 8*1024*512
  u16* kt = qt + 4194304;
  u16* vm = kt + 4194304;
  u16* EP = vm + 4194304;          // 8*1024*1024
  u16* OT = qt;                    // reuse

  qkv_kernel<<<dim3(64, 8), 256, 0, stream>>>(x, Wq, bq, Wk, bk, Wv, bv, qt, kt, vm);
  // E = qt * kt^T / 32   (M=1024, N=1024, K=512), 128x128 tiles
  gemm_nt<4><<<dim3(8, 8, 8), 256, 0, stream>>>(qt, kt, EP, 1024, 1024, 512, 0.03125f);
  softmax_kernel<<<2048, 256, 0, stream>>>(EP);
  // OT[j][m] = P * v^T   (M=1024, N=512, K=1024), 64x128 tiles
  gemm_nt<2><<<dim3(4, 16, 8), 256, 0, stream>>>(EP, vm, OT, 1024, 512, 1024, 1.0f);
  out_kernel<<<512, 256, 0, stream>>>(x, OT, Wo, bo, gm, out);
}